// Round 1
// baseline (114.618 us; speedup 1.0000x reference)
//
#include <hip/hip_runtime.h>
#include <math.h>

// StripePolynomial2d on gfx950.
// Structure: out[b,o,w,h] = 0.25 * sum_{i=0..3} sum_c sum_j W[i,o,c,2*seg+j] * L_j(xl)
// where seg/xl derive from (x[b,c,w,h] + pos_i(w,h)).
// pos_0 == pos_1 bitwise (theta=0 => sin term vanishes), so fold W0+W1 -> 3
// effective stripes. Weights staged in LDS permuted to [e][c][n][o] so the 9
// floats per (e,c,seg) are contiguous (ds_read2-friendly).

#define LDSZ (3 * 3 * 129 * 3) // 3483 floats = 13.9 KB

__global__ __launch_bounds__(256) void stripe_kernel(
    const float* __restrict__ x, const float* __restrict__ Wt,
    float* __restrict__ out)
{
    __shared__ float lw[LDSZ];
    const int tid = threadIdx.x;

    // ---- stage weights into LDS, layout lw[((e*3+c)*129 + n)*3 + o] ----
    for (int idx = tid; idx < LDSZ; idx += 256) {
        int o  = idx % 3;
        int r  = idx / 3;
        int n  = r % 129;
        int r2 = r / 129;
        int c  = r2 % 3;
        int e  = r2 / 3;
        float v;
        if (e == 0) {
            // folded stripes 0+1 (identical positions)
            v = Wt[((0 * 3 + o) * 3 + c) * 129 + n]
              + Wt[((1 * 3 + o) * 3 + c) * 129 + n];
        } else {
            int i = e + 1; // e=1 -> stripe 2, e=2 -> stripe 3
            v = Wt[((i * 3 + o) * 3 + c) * 129 + n];
        }
        lw[idx] = v;
    }
    __syncthreads();

    const int p = blockIdx.x * 256 + tid; // pixel index within one image
    const int b = blockIdx.y;
    const int w = p >> 9;
    const int h = p & 511;

    // ---- positions: replicate numpy float64 math, cast to f32 ----
    const double RATIO = 512.0 / 513.0;
    const double CX = 0.70710678118654757;  // cos(float64(pi/4))
    const double SY = 0.70710678118654746;  // sin(float64(pi/4)) (1 ulp lower)
    float pos[3];
    {
        // stripe 0/1: r = w; min=0, max=511
        double t0 = ((double)w * RATIO) / 511.0;
        pos[0] = (float)((t0 - 0.5) * 512.0);
        // stripe 2: r = CX*w + SY*h; min=0, max=CX*511+SY*511
        double rw = CX * (double)w;
        double rh = SY * (double)h;
        double mx1 = CX * 511.0 + SY * 511.0;
        double t1 = ((rw + rh) * RATIO) / mx1;
        pos[1] = (float)((t1 - 0.5) * 512.0);
        // stripe 3: r = CX*w - SY*h; min=-SY*511, max=CX*511
        double mn2 = -(SY * 511.0);
        double mx2 = CX * 511.0;
        double t2 = (((rw - rh) - mn2) * RATIO) / (mx2 - mn2);
        pos[2] = (float)((t2 - 0.5) * 512.0);
    }

    const int xbase = ((b * 3) << 18) + p;
    float xv[3];
    xv[0] = x[xbase];
    xv[1] = x[xbase + (1 << 18)];
    xv[2] = x[xbase + (2 << 18)];

    const float N1 = -6.123233995736766e-17f; // f32(-cos(pi/2))
    float acc0 = 0.f, acc1 = 0.f, acc2 = 0.f;

    #pragma unroll
    for (int e = 0; e < 3; ++e) {
        const float pe = pos[e];
        #pragma unroll
        for (int c = 0; c < 3; ++c) {
            float dl   = (xv[c] + pe) * (1.0f / 256.0f);
            float tn   = (dl + 1.0f) * 32.0f;
            float segf = floorf(tn);
            segf = fminf(fmaxf(segf, 0.0f), 63.0f);
            int   seg  = (int)segf;
            float xl   = 2.0f * (tn - segf) - 1.0f;

            // Lagrange basis at nodes {-1, N1~0, +1}; divisors are exact pow2
            float u1 = xl - N1;
            float L0 = (u1 * -1.0f) * ((xl - 1.0f) * -0.5f);
            float L1 = (xl + 1.0f) * ((xl - 1.0f) * -1.0f);
            float L2 = ((xl + 1.0f) * 0.5f) * u1;

            int base = ((e * 3 + c) * 129 + 2 * seg) * 3;
            float wv[9];
            #pragma unroll
            for (int k = 0; k < 9; ++k) wv[k] = lw[base + k];

            acc0 += L0 * wv[0] + L1 * wv[3] + L2 * wv[6];
            acc1 += L0 * wv[1] + L1 * wv[4] + L2 * wv[7];
            acc2 += L0 * wv[2] + L1 * wv[5] + L2 * wv[8];
        }
    }

    float* op = out + ((b * 3) << 18) + p;
    op[0]         = acc0 * 0.25f;
    op[1 << 18]   = acc1 * 0.25f;
    op[2 << 18]   = acc2 * 0.25f;
}

extern "C" void kernel_launch(void* const* d_in, const int* in_sizes, int n_in,
                              void* d_out, int out_size, void* d_ws, size_t ws_size,
                              hipStream_t stream) {
    const float* x  = (const float*)d_in[0]; // [8,3,512,512]
    const float* Wt = (const float*)d_in[1]; // [4,3,3,129]
    float* out = (float*)d_out;              // [8,3,512,512]

    dim3 block(256);
    dim3 grid(512 * 512 / 256, 8); // (1024 pixel-blocks, B)
    hipLaunchKernelGGL(stripe_kernel, grid, block, 0, stream, x, Wt, out);
}

// Round 2
// 93.486 us; speedup vs baseline: 1.2260x; 1.2260x over previous
//
#include <hip/hip_runtime.h>
#include <math.h>

// StripePolynomial2d, round 2: monomial-coefficient form.
// out[b,o,p] = sum_e sum_c P_{e,c,seg,o}(xl),  P = c0 + c1*xl + c2*xl^2
// coeffs hold the folded stripe-0+1 table and the global 0.25 scale.
// Coeff table built once by coeff_kernel into d_ws (27648 B), staged to LDS
// as float4 (16B per (ec,seg,o) record -> ds_read_b128 x3 per inner step).

#define NJOBS 1728            // 9 ec * 64 seg * 3 o
#define CBYTES (NJOBS * 16)   // 27648

__device__ __forceinline__ void coeff_compute(const float* __restrict__ Wt, int j,
                                              float4& out4, int& slot) {
    int ec  = j / 192;
    int rem = j - ec * 192;
    int seg = rem / 3;
    int o   = rem - seg * 3;
    int e   = ec / 3;
    int c   = ec - e * 3;
    int nb  = 2 * seg;
    float w0, w1, w2;
    if (e == 0) {
        const float* p0 = Wt + ((0 * 3 + o) * 3 + c) * 129 + nb;
        const float* p1 = Wt + ((1 * 3 + o) * 3 + c) * 129 + nb;
        w0 = p0[0] + p1[0]; w1 = p0[1] + p1[1]; w2 = p0[2] + p1[2];
    } else {
        const float* p = Wt + (((e + 1) * 3 + o) * 3 + c) * 129 + nb;
        w0 = p[0]; w1 = p[1]; w2 = p[2];
    }
    float c0 = 0.25f * w1;
    float c1 = 0.125f * (w2 - w0);
    float c2 = 0.125f * (w0 + w2) - 0.25f * w1;
    out4 = make_float4(c0, c1, c2, 0.0f);
    slot = (ec * 64 + seg) * 3 + o;   // == j, but keep explicit
}

__global__ __launch_bounds__(256) void coeff_kernel(const float* __restrict__ Wt,
                                                    float4* __restrict__ ws) {
    int j = blockIdx.x * 256 + threadIdx.x;
    if (j >= NJOBS) return;
    float4 v; int slot;
    coeff_compute(Wt, j, v, slot);
    ws[slot] = v;
}

template <bool FROM_WS>
__global__ __launch_bounds__(256) void stripe_main(
    const float* __restrict__ x, const float* __restrict__ Wt,
    const float4* __restrict__ ws, float* __restrict__ out)
{
    __shared__ float4 lw[NJOBS];   // 27648 B

    const int tid = threadIdx.x;
    if (FROM_WS) {
        #pragma unroll
        for (int i = 0; i < 7; ++i) {
            int idx = i * 256 + tid;
            if (idx < NJOBS) lw[idx] = ws[idx];
        }
    } else {
        for (int j = tid; j < NJOBS; j += 256) {
            float4 v; int slot;
            coeff_compute(Wt, j, v, slot);
            lw[slot] = v;
        }
    }
    __syncthreads();

    const int p = blockIdx.x * 256 + tid;
    const int b = blockIdx.y;
    const int w = p >> 9;
    const int h = p & 511;

    // q_e = pos_e/8 + 32, evaluated in f32 from compile-time f64 constants.
    constexpr double RATIO = 512.0 / 513.0;
    constexpr double CX = 0x1.6a09e667f3bcdp-1;  // cos(f64 pi/4)
    constexpr double SY = 0x1.6a09e667f3bccp-1;  // sin(f64 pi/4), 1 ulp lower
    constexpr double S0 = RATIO * 64.0 / 511.0;
    constexpr double R2MAX = CX * 511.0 + SY * 511.0;
    constexpr double S2 = RATIO * 64.0 / R2MAX;
    constexpr double MN3 = -(SY * 511.0);
    constexpr double MX3 = CX * 511.0;
    constexpr double S3 = RATIO * 64.0 / (MX3 - MN3);

    const float wf = (float)w, hf = (float)h;
    float q0 = wf * (float)S0;
    float q1 = fmaf(hf, (float)(SY * S2), wf * (float)(CX * S2));
    float q2 = fmaf(hf, (float)(-(SY * S3)),
                    fmaf(wf, (float)(CX * S3), (float)(-MN3 * S3)));

    const int xbase = ((b * 3) << 18) + p;
    float xv[3];
    xv[0] = x[xbase];
    xv[1] = x[xbase + (1 << 18)];
    xv[2] = x[xbase + (2 << 18)];
    float qe[3] = {q0, q1, q2};

    float acc0 = 0.f, acc1 = 0.f, acc2 = 0.f;

    #pragma unroll
    for (int e = 0; e < 3; ++e) {
        const float q = qe[e];
        #pragma unroll
        for (int c = 0; c < 3; ++c) {
            float tn   = fmaf(xv[c], 0.125f, q);
            float segf = floorf(tn);
            segf = fminf(fmaxf(segf, 0.0f), 63.0f);
            int   seg  = (int)segf;
            float xl   = fmaf(tn - segf, 2.0f, -1.0f);

            const float4* kb = lw + ((e * 3 + c) * 64 + seg) * 3;
            float4 k0 = kb[0];
            float4 k1 = kb[1];
            float4 k2 = kb[2];
            acc0 += fmaf(fmaf(k0.z, xl, k0.y), xl, k0.x);
            acc1 += fmaf(fmaf(k1.z, xl, k1.y), xl, k1.x);
            acc2 += fmaf(fmaf(k2.z, xl, k2.y), xl, k2.x);
        }
    }

    float* op = out + ((b * 3) << 18) + p;
    op[0]       = acc0;
    op[1 << 18] = acc1;
    op[2 << 18] = acc2;
}

extern "C" void kernel_launch(void* const* d_in, const int* in_sizes, int n_in,
                              void* d_out, int out_size, void* d_ws, size_t ws_size,
                              hipStream_t stream) {
    const float* x  = (const float*)d_in[0]; // [8,3,512,512]
    const float* Wt = (const float*)d_in[1]; // [4,3,3,129]
    float* out = (float*)d_out;              // [8,3,512,512]

    dim3 block(256);
    dim3 grid(512 * 512 / 256, 8);

    if (ws_size >= (size_t)CBYTES) {
        float4* ws = (float4*)d_ws;
        hipLaunchKernelGGL(coeff_kernel, dim3(7), block, 0, stream, Wt, ws);
        hipLaunchKernelGGL((stripe_main<true>), grid, block, 0, stream, x, Wt, ws, out);
    } else {
        hipLaunchKernelGGL((stripe_main<false>), grid, block, 0, stream,
                           x, Wt, (const float4*)nullptr, out);
    }
}

// Round 3
// 86.300 us; speedup vs baseline: 1.3281x; 1.0833x over previous
//
#include <hip/hip_runtime.h>
#include <hip/hip_fp16.h>
#include <math.h>

// StripePolynomial2d, round 3: fp16-packed monomial coefficients.
// Record per (ec, seg): 9 fp16 coeffs in a 32 B slot ->
// inner step = ds_read_b128 + ds_read_b32 (20 B/lane vs 48 B fp32).
// halves: [c0_0,c0_1][c1_0,c1_1][c2_0,c2_1][c0_2,c1_2][c2_2,0][pad x3]

#define NREC 576              // 9 ec * 64 seg
#define LDSU (NREC * 8)       // 8 uints (32 B) per record
#define CBYTES (NREC * 32)

__device__ __forceinline__ __half2 u2h2(unsigned int u) {
    __half2 h; __builtin_memcpy(&h, &u, 4); return h;
}
__device__ __forceinline__ unsigned int h22u(__half2 h) {
    unsigned int u; __builtin_memcpy(&u, &h, 4); return u;
}

__device__ __forceinline__ void coeff_compute(const float* __restrict__ Wt, int r,
                                              unsigned int rec[8]) {
    int ec  = r >> 6;
    int seg = r & 63;
    int e   = ec / 3;
    int c   = ec - e * 3;
    int nb  = 2 * seg;
    float c0[3], c1[3], c2[3];
    #pragma unroll
    for (int o = 0; o < 3; ++o) {
        float w0, w1, w2;
        if (e == 0) {
            const float* p0 = Wt + ((0 * 3 + o) * 3 + c) * 129 + nb;
            const float* p1 = Wt + ((1 * 3 + o) * 3 + c) * 129 + nb;
            w0 = p0[0] + p1[0]; w1 = p0[1] + p1[1]; w2 = p0[2] + p1[2];
        } else {
            const float* p = Wt + (((e + 1) * 3 + o) * 3 + c) * 129 + nb;
            w0 = p[0]; w1 = p[1]; w2 = p[2];
        }
        c0[o] = 0.25f  * w1;
        c1[o] = 0.125f * (w2 - w0);
        c2[o] = 0.125f * (w0 + w2) - 0.25f * w1;
    }
    rec[0] = h22u(__floats2half2_rn(c0[0], c0[1]));
    rec[1] = h22u(__floats2half2_rn(c1[0], c1[1]));
    rec[2] = h22u(__floats2half2_rn(c2[0], c2[1]));
    rec[3] = h22u(__floats2half2_rn(c0[2], c1[2]));
    rec[4] = h22u(__floats2half2_rn(c2[2], 0.0f));
    rec[5] = 0u; rec[6] = 0u; rec[7] = 0u;
}

__global__ __launch_bounds__(256) void coeff_kernel(const float* __restrict__ Wt,
                                                    uint4* __restrict__ ws) {
    int r = blockIdx.x * 256 + threadIdx.x;
    if (r >= NREC) return;
    unsigned int rec[8];
    coeff_compute(Wt, r, rec);
    ws[2 * r]     = make_uint4(rec[0], rec[1], rec[2], rec[3]);
    ws[2 * r + 1] = make_uint4(rec[4], rec[5], rec[6], rec[7]);
}

template <bool FROM_WS>
__global__ __launch_bounds__(256) void stripe_main(
    const float* __restrict__ x, const float* __restrict__ Wt,
    const uint4* __restrict__ ws, float* __restrict__ out)
{
    __shared__ uint4 lw4[NREC * 2];   // 18432 B
    const unsigned int* lw = (const unsigned int*)lw4;

    const int tid = threadIdx.x;
    if (FROM_WS) {
        #pragma unroll
        for (int i = 0; i < 5; ++i) {
            int idx = i * 256 + tid;
            if (idx < NREC * 2) lw4[idx] = ws[idx];
        }
    } else {
        for (int r = tid; r < NREC; r += 256) {
            unsigned int rec[8];
            coeff_compute(Wt, r, rec);
            lw4[2 * r]     = make_uint4(rec[0], rec[1], rec[2], rec[3]);
            lw4[2 * r + 1] = make_uint4(rec[4], rec[5], rec[6], rec[7]);
        }
    }
    __syncthreads();

    const int p = blockIdx.x * 256 + tid;
    const int b = blockIdx.y;
    const int w = p >> 9;
    const int h = p & 511;

    // q_e = pos_e/8 + 32, f32 from compile-time f64 constants.
    constexpr double RATIO = 512.0 / 513.0;
    constexpr double CX = 0x1.6a09e667f3bcdp-1;  // cos(f64 pi/4)
    constexpr double SY = 0x1.6a09e667f3bccp-1;  // sin(f64 pi/4), 1 ulp lower
    constexpr double S0 = RATIO * 64.0 / 511.0;
    constexpr double R2MAX = CX * 511.0 + SY * 511.0;
    constexpr double S2 = RATIO * 64.0 / R2MAX;
    constexpr double MN3 = -(SY * 511.0);
    constexpr double MX3 = CX * 511.0;
    constexpr double S3 = RATIO * 64.0 / (MX3 - MN3);

    const float wf = (float)w, hf = (float)h;
    float qe[3];
    qe[0] = wf * (float)S0;
    qe[1] = fmaf(hf, (float)(SY * S2), wf * (float)(CX * S2));
    qe[2] = fmaf(hf, (float)(-(SY * S3)),
                 fmaf(wf, (float)(CX * S3), (float)(-MN3 * S3)));

    const int xbase = ((b * 3) << 18) + p;
    float xv[3];
    xv[0] = x[xbase];
    xv[1] = x[xbase + (1 << 18)];
    xv[2] = x[xbase + (2 << 18)];

    float acc0 = 0.f, acc1 = 0.f, acc2 = 0.f;

    #pragma unroll
    for (int e = 0; e < 3; ++e) {
        const float q = qe[e];
        #pragma unroll
        for (int c = 0; c < 3; ++c) {
            float tn   = fmaf(xv[c], 0.125f, q);
            float segf = fminf(fmaxf(floorf(tn), 0.0f), 63.0f);
            int   seg  = (int)segf;
            float xl   = fmaf(tn - segf, 2.0f, -1.0f);

            const unsigned int* rp = lw + (((e * 3 + c) * 64 + seg) << 3);
            uint4 A = *(const uint4*)rp;      // ds_read_b128
            unsigned int Bv = rp[4];          // ds_read_b32
            float2 k0 = __half22float2(u2h2(A.x));  // c0_0, c0_1
            float2 k1 = __half22float2(u2h2(A.y));  // c1_0, c1_1
            float2 k2 = __half22float2(u2h2(A.z));  // c2_0, c2_1
            float2 k3 = __half22float2(u2h2(A.w));  // c0_2, c1_2
            float  c22 = __half2float(__low2half(u2h2(Bv)));

            acc0 += fmaf(fmaf(k2.x, xl, k1.x), xl, k0.x);
            acc1 += fmaf(fmaf(k2.y, xl, k1.y), xl, k0.y);
            acc2 += fmaf(fmaf(c22,  xl, k3.y), xl, k3.x);
        }
    }

    float* op = out + ((b * 3) << 18) + p;
    op[0]       = acc0;
    op[1 << 18] = acc1;
    op[2 << 18] = acc2;
}

extern "C" void kernel_launch(void* const* d_in, const int* in_sizes, int n_in,
                              void* d_out, int out_size, void* d_ws, size_t ws_size,
                              hipStream_t stream) {
    const float* x  = (const float*)d_in[0]; // [8,3,512,512]
    const float* Wt = (const float*)d_in[1]; // [4,3,3,129]
    float* out = (float*)d_out;              // [8,3,512,512]

    dim3 block(256);
    dim3 grid(512 * 512 / 256, 8);

    if (ws_size >= (size_t)CBYTES) {
        uint4* ws = (uint4*)d_ws;
        hipLaunchKernelGGL(coeff_kernel, dim3(3), block, 0, stream, Wt, ws);
        hipLaunchKernelGGL((stripe_main<true>), grid, block, 0, stream, x, Wt, ws, out);
    } else {
        hipLaunchKernelGGL((stripe_main<false>), grid, block, 0, stream,
                           x, Wt, (const uint4*)nullptr, out);
    }
}

// Round 4
// 84.568 us; speedup vs baseline: 1.3553x; 1.0205x over previous
//
#include <hip/hip_runtime.h>
#include <hip/hip_fp16.h>
#include <math.h>

// StripePolynomial2d, round 4: three-phase restructure to batch LDS reads.
// Phase A: all 9 (seg, xl); Phase B: all 9 ds_read_b128 + ds_read_b32 into
// register arrays (18 outstanding LDS ops -> latency hidden); Phase C:
// f16->f32 convert + Horner + accumulate. Record layout unchanged from R3:
// 32 B per (ec,seg): [c0_0,c0_1][c1_0,c1_1][c2_0,c2_1][c0_2,c1_2][c2_2,0]+pad.

#define NREC 576              // 9 ec * 64 seg
#define CBYTES (NREC * 32)

__device__ __forceinline__ __half2 u2h2(unsigned int u) {
    __half2 h; __builtin_memcpy(&h, &u, 4); return h;
}
__device__ __forceinline__ unsigned int h22u(__half2 h) {
    unsigned int u; __builtin_memcpy(&u, &h, 4); return u;
}

__device__ __forceinline__ void coeff_compute(const float* __restrict__ Wt, int r,
                                              unsigned int rec[8]) {
    int ec  = r >> 6;
    int seg = r & 63;
    int e   = ec / 3;
    int c   = ec - e * 3;
    int nb  = 2 * seg;
    float c0[3], c1[3], c2[3];
    #pragma unroll
    for (int o = 0; o < 3; ++o) {
        float w0, w1, w2;
        if (e == 0) {
            const float* p0 = Wt + ((0 * 3 + o) * 3 + c) * 129 + nb;
            const float* p1 = Wt + ((1 * 3 + o) * 3 + c) * 129 + nb;
            w0 = p0[0] + p1[0]; w1 = p0[1] + p1[1]; w2 = p0[2] + p1[2];
        } else {
            const float* p = Wt + (((e + 1) * 3 + o) * 3 + c) * 129 + nb;
            w0 = p[0]; w1 = p[1]; w2 = p[2];
        }
        c0[o] = 0.25f  * w1;
        c1[o] = 0.125f * (w2 - w0);
        c2[o] = 0.125f * (w0 + w2) - 0.25f * w1;
    }
    rec[0] = h22u(__floats2half2_rn(c0[0], c0[1]));
    rec[1] = h22u(__floats2half2_rn(c1[0], c1[1]));
    rec[2] = h22u(__floats2half2_rn(c2[0], c2[1]));
    rec[3] = h22u(__floats2half2_rn(c0[2], c1[2]));
    rec[4] = h22u(__floats2half2_rn(c2[2], 0.0f));
    rec[5] = 0u; rec[6] = 0u; rec[7] = 0u;
}

__global__ __launch_bounds__(256) void coeff_kernel(const float* __restrict__ Wt,
                                                    uint4* __restrict__ ws) {
    int r = blockIdx.x * 256 + threadIdx.x;
    if (r >= NREC) return;
    unsigned int rec[8];
    coeff_compute(Wt, r, rec);
    ws[2 * r]     = make_uint4(rec[0], rec[1], rec[2], rec[3]);
    ws[2 * r + 1] = make_uint4(rec[4], rec[5], rec[6], rec[7]);
}

template <bool FROM_WS>
__global__ __launch_bounds__(256) void stripe_main(
    const float* __restrict__ x, const float* __restrict__ Wt,
    const uint4* __restrict__ ws, float* __restrict__ out)
{
    __shared__ uint4 lw4[NREC * 2];   // 18432 B
    const unsigned int* lw = (const unsigned int*)lw4;

    const int tid = threadIdx.x;
    if (FROM_WS) {
        #pragma unroll
        for (int i = 0; i < 5; ++i) {
            int idx = i * 256 + tid;
            if (idx < NREC * 2) lw4[idx] = ws[idx];
        }
    } else {
        for (int r = tid; r < NREC; r += 256) {
            unsigned int rec[8];
            coeff_compute(Wt, r, rec);
            lw4[2 * r]     = make_uint4(rec[0], rec[1], rec[2], rec[3]);
            lw4[2 * r + 1] = make_uint4(rec[4], rec[5], rec[6], rec[7]);
        }
    }
    __syncthreads();

    const int p = blockIdx.x * 256 + tid;
    const int b = blockIdx.y;
    const int w = p >> 9;
    const int h = p & 511;

    // q_e = pos_e/8 + 32, f32 from compile-time f64 constants.
    constexpr double RATIO = 512.0 / 513.0;
    constexpr double CX = 0x1.6a09e667f3bcdp-1;  // cos(f64 pi/4)
    constexpr double SY = 0x1.6a09e667f3bccp-1;  // sin(f64 pi/4), 1 ulp lower
    constexpr double S0 = RATIO * 64.0 / 511.0;
    constexpr double R2MAX = CX * 511.0 + SY * 511.0;
    constexpr double S2 = RATIO * 64.0 / R2MAX;
    constexpr double MN3 = -(SY * 511.0);
    constexpr double MX3 = CX * 511.0;
    constexpr double S3 = RATIO * 64.0 / (MX3 - MN3);

    const float wf = (float)w, hf = (float)h;
    float qe[3];
    qe[0] = wf * (float)S0;
    qe[1] = fmaf(hf, (float)(SY * S2), wf * (float)(CX * S2));
    qe[2] = fmaf(hf, (float)(-(SY * S3)),
                 fmaf(wf, (float)(CX * S3), (float)(-MN3 * S3)));

    const int xbase = ((b * 3) << 18) + p;
    float xv[3];
    xv[0] = x[xbase];
    xv[1] = x[xbase + (1 << 18)];
    xv[2] = x[xbase + (2 << 18)];

    // ---- Phase A: all 9 (seg, xl) ----
    int   segi[9];
    float xls[9];
    #pragma unroll
    for (int s = 0; s < 9; ++s) {
        int e = s / 3, c = s - 3 * (s / 3);
        float tn   = fmaf(xv[c], 0.125f, qe[e]);
        float segf = fminf(fmaxf(floorf(tn), 0.0f), 63.0f);
        segi[s] = (int)segf;
        xls[s]  = fmaf(tn - segf, 2.0f, -1.0f);
    }

    // ---- Phase B: batch all LDS reads (18 outstanding) ----
    uint4        A[9];
    unsigned int Bv[9];
    #pragma unroll
    for (int s = 0; s < 9; ++s) {
        const unsigned int* rp = lw + ((s * 64 + segi[s]) << 3);
        A[s]  = *(const uint4*)rp;   // ds_read_b128
        Bv[s] = rp[4];               // ds_read_b32
    }

    // ---- Phase C: convert + Horner + accumulate ----
    float acc0 = 0.f, acc1 = 0.f, acc2 = 0.f;
    #pragma unroll
    for (int s = 0; s < 9; ++s) {
        float  xl  = xls[s];
        float2 k0 = __half22float2(u2h2(A[s].x));  // c0_0, c0_1
        float2 k1 = __half22float2(u2h2(A[s].y));  // c1_0, c1_1
        float2 k2 = __half22float2(u2h2(A[s].z));  // c2_0, c2_1
        float2 k3 = __half22float2(u2h2(A[s].w));  // c0_2, c1_2
        float  c22 = __half2float(__low2half(u2h2(Bv[s])));
        acc0 += fmaf(fmaf(k2.x, xl, k1.x), xl, k0.x);
        acc1 += fmaf(fmaf(k2.y, xl, k1.y), xl, k0.y);
        acc2 += fmaf(fmaf(c22,  xl, k3.y), xl, k3.x);
    }

    float* op = out + ((b * 3) << 18) + p;
    op[0]       = acc0;
    op[1 << 18] = acc1;
    op[2 << 18] = acc2;
}

extern "C" void kernel_launch(void* const* d_in, const int* in_sizes, int n_in,
                              void* d_out, int out_size, void* d_ws, size_t ws_size,
                              hipStream_t stream) {
    const float* x  = (const float*)d_in[0]; // [8,3,512,512]
    const float* Wt = (const float*)d_in[1]; // [4,3,3,129]
    float* out = (float*)d_out;              // [8,3,512,512]

    dim3 block(256);
    dim3 grid(512 * 512 / 256, 8);

    if (ws_size >= (size_t)CBYTES) {
        uint4* ws = (uint4*)d_ws;
        hipLaunchKernelGGL(coeff_kernel, dim3(3), block, 0, stream, Wt, ws);
        hipLaunchKernelGGL((stripe_main<true>), grid, block, 0, stream, x, Wt, ws, out);
    } else {
        hipLaunchKernelGGL((stripe_main<false>), grid, block, 0, stream,
                           x, Wt, (const uint4*)nullptr, out);
    }
}